// Round 7
// baseline (629.958 us; speedup 1.0000x reference)
//
#include <hip/hip_runtime.h>
#include <cstdint>
#include <cstddef>

#define H 4
#define DK 128
#define DV 256
#define NH 2
#define HID 1024
#define KSZ 4
#define NTOT 4608  // packed projection width: 512 q | 1024 k | 2048 v | 1024 g

typedef __bf16 bfx8 __attribute__((ext_vector_type(8)));
typedef float f32x4 __attribute__((ext_vector_type(4)));

__device__ __forceinline__ float wave_sum(float x) {
#pragma unroll
  for (int off = 1; off < 64; off <<= 1) x += __shfl_xor(x, off, 64);
  return x;
}

__device__ __forceinline__ ushort f2bf(float x) {
  uint u = __float_as_uint(x);
  return (ushort)((u + 0x7fffu + ((u >> 16) & 1u)) >> 16);
}

#define DPP_ADD(x, ctrl) \
  x += __int_as_float(__builtin_amdgcn_update_dpp(0, __float_as_int(x), ctrl, 0xf, 0xf, true))

// three independent full-wave64 sums, DPP chains interleaved for latency hiding
__device__ __forceinline__ void dpp_sum3(float& a, float& b, float& c) {
#define DPP_L(ctrl) DPP_ADD(a, ctrl); DPP_ADD(b, ctrl); DPP_ADD(c, ctrl);
  DPP_L(0x111)  // row_shr:1
  DPP_L(0x112)  // row_shr:2
  DPP_L(0x114)  // row_shr:4
  DPP_L(0x118)  // row_shr:8
  DPP_L(0x142)  // row_bcast:15
  DPP_L(0x143)  // row_bcast:31
#undef DPP_L
  a = __int_as_float(__builtin_amdgcn_readlane(__float_as_int(a), 63));
  b = __int_as_float(__builtin_amdgcn_readlane(__float_as_int(b), 63));
  c = __int_as_float(__builtin_amdgcn_readlane(__float_as_int(c), 63));
}

// ---------------- fp32 -> bf16 cast, 4 elems/thread
__global__ __launch_bounds__(256) void cast_hs(const float* __restrict__ src,
                                               ushort* __restrict__ dst) {
  int i = blockIdx.x * 256 + threadIdx.x;
  float4 v = ((const float4*)src)[i];
  ushort4 o = {f2bf(v.x), f2bf(v.y), f2bf(v.z), f2bf(v.w)};
  ((ushort4*)dst)[i] = o;
}

// ---------------- transpose+cast packed weights: Bt[4608][1024] bf16, Bt[n][k] = W*[k][n]
__global__ __launch_bounds__(256) void tr_pack(const float* __restrict__ Wq,
                                               const float* __restrict__ Wk,
                                               const float* __restrict__ Wv,
                                               const float* __restrict__ Wg,
                                               ushort* __restrict__ Bt) {
  __shared__ float tile[32][33];
  int n0 = blockIdx.x * 32, k0 = blockIdx.y * 32;
  const float* src;
  int ld, nb;
  if (n0 < 512)       { src = Wq; ld = 512;  nb = n0; }
  else if (n0 < 1536) { src = Wk; ld = 1024; nb = n0 - 512; }
  else if (n0 < 3584) { src = Wv; ld = 2048; nb = n0 - 1536; }
  else                { src = Wg; ld = 1024; nb = n0 - 3584; }
  int tx = threadIdx.x & 31, ty = threadIdx.x >> 5;
#pragma unroll
  for (int i = 0; i < 4; i++)
    tile[ty + i * 8][tx] = src[(size_t)(k0 + ty + i * 8) * ld + nb + tx];
  __syncthreads();
#pragma unroll
  for (int i = 0; i < 4; i++)
    Bt[(size_t)(n0 + ty + i * 8) * 1024 + k0 + tx] = f2bf(tile[tx][ty + i * 8]);
}

// ---------------- transpose+cast single square matrix (Wo): Bt[n][k] = W[k][n]
__global__ __launch_bounds__(256) void tr_one(const float* __restrict__ W,
                                              ushort* __restrict__ Bt, int N) {
  __shared__ float tile[32][33];
  int n0 = blockIdx.x * 32, k0 = blockIdx.y * 32;
  int tx = threadIdx.x & 31, ty = threadIdx.x >> 5;
#pragma unroll
  for (int i = 0; i < 4; i++)
    tile[ty + i * 8][tx] = W[(size_t)(k0 + ty + i * 8) * N + n0 + tx];
  __syncthreads();
#pragma unroll
  for (int i = 0; i < 4; i++)
    Bt[(size_t)(n0 + ty + i * 8) * 1024 + k0 + tx] = f2bf(tile[tx][ty + i * 8]);
}

// ---------------- bf16 MFMA GEMM: C[M,N](fp32, ldc) = A[M,K]bf16 @ Bt[N,K]bf16^T
// 128x128 tile, BK=32, 4 waves (2x2), each wave 64x64 via 4x4 16x16x32 MFMAs.
#define LDP 40  // padded LDS stride (ushorts): 80B -> bank stride 20 -> 2-way (free)
__global__ __launch_bounds__(256) void gemm_bf16(const ushort* __restrict__ A,
                                                 const ushort* __restrict__ Bt,
                                                 float* __restrict__ C,
                                                 int K, int ldc) {
  __shared__ __align__(16) ushort As[128][LDP];
  __shared__ __align__(16) ushort Bs[128][LDP];
  const int tid = threadIdx.x;
  const int lane = tid & 63, wave = tid >> 6;
  const int wr = wave >> 1, wc = wave & 1;
  const int row0 = blockIdx.y * 128, col0 = blockIdx.x * 128;
  const int r = tid >> 1, hf = tid & 1;

  f32x4 acc[4][4];
#pragma unroll
  for (int i = 0; i < 4; i++)
#pragma unroll
    for (int j = 0; j < 4; j++) acc[i][j] = {0.f, 0.f, 0.f, 0.f};

  const int lrow = lane & 15, lk = (lane >> 4) * 8;

  for (int k0 = 0; k0 < K; k0 += 32) {
    // stage: thread handles 32B of one row of each tile
    const float4* pa = (const float4*)(A + (size_t)(row0 + r) * K + k0 + hf * 16);
    const float4* pb = (const float4*)(Bt + (size_t)(col0 + r) * K + k0 + hf * 16);
    float4 a0 = pa[0], a1 = pa[1];
    float4 b0 = pb[0], b1 = pb[1];
    __syncthreads();  // previous compute done reading LDS
    *(float4*)&As[r][hf * 16] = a0;
    *(float4*)&As[r][hf * 16 + 8] = a1;
    *(float4*)&Bs[r][hf * 16] = b0;
    *(float4*)&Bs[r][hf * 16 + 8] = b1;
    __syncthreads();
    bfx8 af[4], bf[4];
#pragma unroll
    for (int mf = 0; mf < 4; mf++)
      af[mf] = *(const bfx8*)&As[wr * 64 + mf * 16 + lrow][lk];
#pragma unroll
    for (int nf = 0; nf < 4; nf++)
      bf[nf] = *(const bfx8*)&Bs[wc * 64 + nf * 16 + lrow][lk];
#pragma unroll
    for (int mf = 0; mf < 4; mf++)
#pragma unroll
      for (int nf = 0; nf < 4; nf++)
        acc[mf][nf] = __builtin_amdgcn_mfma_f32_16x16x32_bf16(af[mf], bf[nf], acc[mf][nf], 0, 0, 0);
  }
  // epilogue: C/D layout col=lane&15, row=(lane>>4)*4+reg  [m89/m91 verified]
  const int crow = (lane >> 4) * 4, ccol = lane & 15;
#pragma unroll
  for (int mf = 0; mf < 4; mf++)
#pragma unroll
    for (int nf = 0; nf < 4; nf++)
#pragma unroll
      for (int rr = 0; rr < 4; rr++)
        C[(size_t)(row0 + wr * 64 + mf * 16 + crow + rr) * ldc + col0 + wc * 64 + nf * 16 + ccol] =
            acc[mf][nf][rr];
}

// ---------------- beta / g tiny projections with fused activations
__global__ __launch_bounds__(256) void proj_bg(const float* __restrict__ hs,
                                               const float* __restrict__ Wb,
                                               const float* __restrict__ Wa,
                                               const float* __restrict__ A_log,
                                               const float* __restrict__ dt_bias,
                                               float* __restrict__ beta,
                                               float* __restrict__ g) {
  int row = blockIdx.x;
  int lane = threadIdx.x & 63;
  int wave = threadIdx.x >> 6;
  const float* x = hs + (size_t)row * HID;
  for (int out = wave; out < 12; out += 4) {
    float sum = 0.f;
    if (out < 8) {
      for (int k = lane; k < HID; k += 64) sum = fmaf(x[k], Wb[(size_t)k * 8 + out], sum);
    } else {
      int c = out - 8;
      for (int k = lane; k < HID; k += 64) sum = fmaf(x[k], Wa[(size_t)k * 4 + c], sum);
    }
    sum = wave_sum(sum);
    if (lane == 0) {
      if (out < 8) {
        beta[(size_t)row * 8 + out] = 2.f / (1.f + expf(-sum));
      } else {
        int h = out - 8;
        float xx = sum + dt_bias[h];
        float sp = (xx > 20.f) ? xx : log1pf(expf(xx));
        g[(size_t)row * 4 + h] = -expf(A_log[h]) * sp;
      }
    }
  }
}

// ---------------- causal depthwise conv(K=4) + SiLU (+ optional l2norm over D)
template <int D, bool NORM>
__global__ __launch_bounds__(D) void conv_silu(const float* __restrict__ x, int ldx,
                                               const float* __restrict__ w,
                                               float* __restrict__ y,
                                               int T, int C, int G, float eps) {
  int rb = blockIdx.x;
  int gi = rb % G;
  int bt = rb / G;
  int t = bt % T;
  int b = bt / T;
  int c = gi * D + threadIdx.x;
  const float* wc = w + (size_t)c * KSZ;
  float acc = 0.f;
#pragma unroll
  for (int i = 0; i < KSZ; i++) {
    int tt = t - (KSZ - 1) + i;
    if (tt >= 0) acc = fmaf(x[(size_t)(b * T + tt) * ldx + c], wc[i], acc);
  }
  float val = acc / (1.f + expf(-acc));
  if constexpr (NORM) {
    float ss = wave_sum(val * val);
    constexpr int NW = D / 64;
    __shared__ float sred[NW];
    if ((threadIdx.x & 63) == 0) sred[threadIdx.x >> 6] = ss;
    __syncthreads();
    float tot = 0.f;
#pragma unroll
    for (int i = 0; i < NW; i++) tot += sred[i];
    val *= rsqrtf(tot + eps);
  }
  y[(size_t)(b * T + t) * C + c] = val;
}

// ---------------- cross dots: d01 = k0.k1, e0 = q.k0, e1 = q.k1 per (bt,h)
__global__ __launch_bounds__(256) void cross_dots(const float* __restrict__ q,
                                                  const float* __restrict__ k,
                                                  float* __restrict__ dots) {
  int idx = blockIdx.x * 4 + (threadIdx.x >> 6);  // bt*H + h
  int lane = threadIdx.x & 63;
  int bt = idx >> 2, h = idx & 3;
  const float2* q2 = (const float2*)q;
  const float2* k2 = (const float2*)k;
  float2 qq = q2[((size_t)bt * H + h) * 64 + lane];
  float2 ka = k2[((size_t)(bt * NH + 0) * H + h) * 64 + lane];
  float2 kb = k2[((size_t)(bt * NH + 1) * H + h) * 64 + lane];
  float d01 = ka.x * kb.x + ka.y * kb.y;
  float e0 = qq.x * ka.x + qq.y * ka.y;
  float e1 = qq.x * kb.x + qq.y * kb.y;
  dpp_sum3(d01, e0, e1);
  if (lane == 0) {
    float4 o4 = {d01, e0, e1, 0.f};
    *(float4*)&dots[(size_t)idx * 4] = o4;
  }
}

// ---------------- sequential gated-delta scan, one wave per (b,h,dv-column)
// XCD-local: bh = blockIdx%8 pins each (b,h)'s 64 blocks to one XCD (L2-resident).
// 4-deep register prefetch FIFO (named slots, statically unrolled).
// __launch_bounds__(256, 2): grid gives only 2 blocks/CU -> allow up to 256 VGPR so
// the prefetch FIFO stays register-resident (at default the compiler allocated 56
// VGPR for 8-wave occupancy we can never reach, sinking the prefetch loads).
__global__ __launch_bounds__(256, 2) void scan_kernel(const float* __restrict__ q,
                                                   const float* __restrict__ k,
                                                   const float* __restrict__ v,
                                                   const float* __restrict__ beta,
                                                   const float* __restrict__ g,
                                                   const float* __restrict__ dots,
                                                   float* __restrict__ o,
                                                   int T) {
  const int wave = threadIdx.x >> 6, lane = threadIdx.x & 63;
  const int bh = blockIdx.x & 7;   // -> XCD-local
  const int cb = blockIdx.x >> 3;
  const int b = bh >> 2, h = bh & 3;
  const int col = cb * 4 + wave;
  const float2* q2 = (const float2*)q;
  const float2* k2 = (const float2*)k;
  const float4* d4 = (const float4*)dots;
  float2 s = {0.f, 0.f};

  float2 Aka, Akb, Aqq; float Ava, Avb, Abea, Abeb, Agg; float4 Add;
  float2 Bka, Bkb, Bqq; float Bva, Bvb, Bbea, Bbeb, Bgg; float4 Bdd;
  float2 Cka, Ckb, Cqq; float Cva, Cvb, Cbea, Cbeb, Cgg; float4 Cdd;
  float2 Dka, Dkb, Dqq; float Dva, Dvb, Dbea, Dbeb, Dgg; float4 Ddd;

#define LOADQ(P, tt) { \
    int btn_ = b * T + (tt); \
    P##ka = k2[((size_t)(btn_ * NH + 0) * H + h) * 64 + lane]; \
    P##kb = k2[((size_t)(btn_ * NH + 1) * H + h) * 64 + lane]; \
    P##qq = q2[((size_t)btn_ * H + h) * 64 + lane]; \
    P##va = v[((size_t)(btn_ * NH + 0) * H + h) * DV + col]; \
    P##vb = v[((size_t)(btn_ * NH + 1) * H + h) * DV + col]; \
    P##bea = beta[(size_t)(btn_ * NH + 0) * H + h]; \
    P##beb = beta[(size_t)(btn_ * NH + 1) * H + h]; \
    P##gg = g[(size_t)btn_ * H + h]; \
    P##dd = d4[(size_t)btn_ * H + h]; }

#define STEPQ(P, tt) { \
    float gam = __expf(P##gg); \
    float p0 = P##ka.x * s.x + P##ka.y * s.y; \
    float p1 = P##kb.x * s.x + P##kb.y * s.y; \
    float pq = P##qq.x * s.x + P##qq.y * s.y; \
    dpp_sum3(p0, p1, pq); \
    float gb0 = P##bea * gam, gb1 = P##beb * gam, bd = P##beb * P##dd.x; \
    float t0 = P##bea * P##va, t1 = P##beb * P##vb; \
    float c0 = fmaf(-gb0, p0, t0); \
    float c1 = fmaf(-bd, c0, fmaf(-gb1, p1, t1)); \
    float ov = fmaf(c1, P##dd.z, fmaf(c0, P##dd.y, gam * pq)); \
    s.x = fmaf(gam, s.x, fmaf(c0, P##ka.x, c1 * P##kb.x)); \
    s.y = fmaf(gam, s.y, fmaf(c0, P##ka.y, c1 * P##kb.y)); \
    if (lane == 0) o[(size_t)(b * T + (tt)) * NTOT + h * 256 + col] = ov; }

  LOADQ(A, 0)
  LOADQ(B, 1)
  LOADQ(C, 2)
  LOADQ(D, 3)
  int t = 0;
  for (; t + 4 < T; t += 4) {
    STEPQ(A, t)     LOADQ(A, t + 4)
    STEPQ(B, t + 1) LOADQ(B, t + 5)
    STEPQ(C, t + 2) LOADQ(C, t + 6)
    STEPQ(D, t + 3) LOADQ(D, t + 7)
  }
  STEPQ(A, t)
  STEPQ(B, t + 1)
  STEPQ(C, t + 2)
  STEPQ(D, t + 3)
#undef LOADQ
#undef STEPQ
}

// ---------------- RMSNorm(o) * w * SiLU(gate); writes dense bf16 [M][1024]
__global__ __launch_bounds__(256) void post_norm_gate(const float* __restrict__ o,
                                                      const float* __restrict__ gate,
                                                      const float* __restrict__ w,
                                                      ushort* __restrict__ obf) {
  int rb = blockIdx.x;  // bt*H + h
  int bt = rb >> 2, h = rb & 3;
  int tid = threadIdx.x;
  size_t ob = (size_t)bt * NTOT + h * 256 + tid;
  float ov = o[ob];
  float ss = wave_sum(ov * ov);
  __shared__ float sred[4];
  if ((tid & 63) == 0) sred[tid >> 6] = ss;
  __syncthreads();
  float tot = sred[0] + sred[1] + sred[2] + sred[3];
  float rms = rsqrtf(tot * (1.f / 256.f) + 1e-5f);
  float gt = gate[(size_t)bt * NTOT + h * 256 + tid];
  float val = ov * rms * w[tid] * (gt / (1.f + expf(-gt)));
  obf[(size_t)bt * HID + h * 256 + tid] = f2bf(val);
}

extern "C" void kernel_launch(void* const* d_in, const int* in_sizes, int n_in,
                              void* d_out, int out_size, void* d_ws, size_t ws_size,
                              hipStream_t stream) {
  const float* hs      = (const float*)d_in[0];
  const float* Wq      = (const float*)d_in[1];
  const float* Wk      = (const float*)d_in[2];
  const float* Wv      = (const float*)d_in[3];
  const float* Wb      = (const float*)d_in[4];
  const float* Wa      = (const float*)d_in[5];
  const float* Wg      = (const float*)d_in[6];
  const float* Wo      = (const float*)d_in[7];
  const float* A_log   = (const float*)d_in[8];
  const float* dt_bias = (const float*)d_in[9];
  const float* wq_conv = (const float*)d_in[10];
  const float* wk_conv = (const float*)d_in[11];
  const float* wv_conv = (const float*)d_in[12];
  const float* o_w     = (const float*)d_in[13];
  float* out = (float*)d_out;

  const int B = 2, T = 1024, M = B * T;

  float* ws    = (float*)d_ws;
  float* qkvg  = ws;                          // M*4608 fp32; cols 0..1023 reused for o
  float* kbuf  = qkvg + (size_t)M * NTOT;     // M*1024 fp32
  float* vbuf  = kbuf + (size_t)M * 1024;     // M*2048 fp32
  float* betab = vbuf + (size_t)M * 2048;     // M*8
  float* gb    = betab + (size_t)M * 8;       // M*4
  float* dotsb = gb + (size_t)M * 4;          // M*H*4
  float* qbuf  = out;                         // M*512 scratch in d_out; overwritten at end

  // time-disjoint bf16 aliases inside kbuf/vbuf regions:
  ushort* bqkvgT = (ushort*)kbuf;
  ushort* hsb    = (ushort*)(vbuf + (size_t)524288);  // vbuf + 2MB
  ushort* woT = (ushort*)kbuf;
  ushort* obf = (ushort*)vbuf;

  // casts
  cast_hs<<<(M * HID / 4) / 256, 256, 0, stream>>>(hs, hsb);
  tr_pack<<<dim3(NTOT / 32, HID / 32), 256, 0, stream>>>(Wq, Wk, Wv, Wg, bqkvgT);
  // fused projections (bf16 MFMA) -> packed fp32 [M,4608]
  gemm_bf16<<<dim3(NTOT / 128, M / 128), 256, 0, stream>>>(hsb, bqkvgT, qkvg, HID, NTOT);
  // beta / g
  proj_bg<<<M, 256, 0, stream>>>(hs, Wb, Wa, A_log, dt_bias, betab, gb);
  // conv + SiLU (+ l2norm for q,k); overwrite kbuf/vbuf (bf16 staging dead now)
  conv_silu<128, true><<<M * 4, 128, 0, stream>>>(qkvg + 0, NTOT, wq_conv, qbuf, T, 512, 4, 1e-6f);
  conv_silu<128, true><<<M * 8, 128, 0, stream>>>(qkvg + 512, NTOT, wk_conv, kbuf, T, 1024, 8, 1e-6f);
  conv_silu<256, false><<<M * 8, 256, 0, stream>>>(qkvg + 1536, NTOT, wv_conv, vbuf, T, 2048, 8, 1e-6f);
  // cross dots (on post-conv q,k)
  cross_dots<<<M * H / 4, 256, 0, stream>>>(qbuf, kbuf, dotsb);
  // scan: o written strided into qkvg cols 0..1023
  scan_kernel<<<512, 256, 0, stream>>>(qbuf, kbuf, vbuf, betab, gb, dotsb, qkvg, T);
  // epilogue norm/gate -> dense bf16 obf (vbuf region, dead after scan)
  post_norm_gate<<<M * H, 256, 0, stream>>>(qkvg, qkvg + 3584, o_w, obf);
  // output projection (bf16 MFMA): Wo^T cast into kbuf region (dead after scan)
  tr_one<<<dim3(HID / 32, HID / 32), 256, 0, stream>>>(Wo, woT, HID);
  gemm_bf16<<<dim3(HID / 128, M / 128), 256, 0, stream>>>(obf, woT, out, HID, HID);
}

// Round 8
// 616.226 us; speedup vs baseline: 1.0223x; 1.0223x over previous
//
#include <hip/hip_runtime.h>
#include <cstdint>
#include <cstddef>

#define H 4
#define DK 128
#define DV 256
#define NH 2
#define HID 1024
#define KSZ 4
#define NTOT 4608  // packed projection width: 512 q | 1024 k | 2048 v | 1024 g

typedef __bf16 bfx8 __attribute__((ext_vector_type(8)));
typedef float f32x4 __attribute__((ext_vector_type(4)));

__device__ __forceinline__ float wave_sum(float x) {
#pragma unroll
  for (int off = 1; off < 64; off <<= 1) x += __shfl_xor(x, off, 64);
  return x;
}

__device__ __forceinline__ ushort f2bf(float x) {
  uint u = __float_as_uint(x);
  return (ushort)((u + 0x7fffu + ((u >> 16) & 1u)) >> 16);
}

#define DPP_ADD(x, ctrl) \
  x += __int_as_float(__builtin_amdgcn_update_dpp(0, __float_as_int(x), ctrl, 0xf, 0xf, true))

// three independent full-wave64 sums, DPP chains interleaved for latency hiding
__device__ __forceinline__ void dpp_sum3(float& a, float& b, float& c) {
#define DPP_L(ctrl) DPP_ADD(a, ctrl); DPP_ADD(b, ctrl); DPP_ADD(c, ctrl);
  DPP_L(0x111)  // row_shr:1
  DPP_L(0x112)  // row_shr:2
  DPP_L(0x114)  // row_shr:4
  DPP_L(0x118)  // row_shr:8
  DPP_L(0x142)  // row_bcast:15
  DPP_L(0x143)  // row_bcast:31
#undef DPP_L
  a = __int_as_float(__builtin_amdgcn_readlane(__float_as_int(a), 63));
  b = __int_as_float(__builtin_amdgcn_readlane(__float_as_int(b), 63));
  c = __int_as_float(__builtin_amdgcn_readlane(__float_as_int(c), 63));
}

// ---------------- fp32 -> bf16 cast, 4 elems/thread
__global__ __launch_bounds__(256) void cast_hs(const float* __restrict__ src,
                                               ushort* __restrict__ dst) {
  int i = blockIdx.x * 256 + threadIdx.x;
  float4 v = ((const float4*)src)[i];
  ushort4 o = {f2bf(v.x), f2bf(v.y), f2bf(v.z), f2bf(v.w)};
  ((ushort4*)dst)[i] = o;
}

// ---------------- transpose+cast packed weights: Bt[4608][1024] bf16, Bt[n][k] = W*[k][n]
__global__ __launch_bounds__(256) void tr_pack(const float* __restrict__ Wq,
                                               const float* __restrict__ Wk,
                                               const float* __restrict__ Wv,
                                               const float* __restrict__ Wg,
                                               ushort* __restrict__ Bt) {
  __shared__ float tile[32][33];
  int n0 = blockIdx.x * 32, k0 = blockIdx.y * 32;
  const float* src;
  int ld, nb;
  if (n0 < 512)       { src = Wq; ld = 512;  nb = n0; }
  else if (n0 < 1536) { src = Wk; ld = 1024; nb = n0 - 512; }
  else if (n0 < 3584) { src = Wv; ld = 2048; nb = n0 - 1536; }
  else                { src = Wg; ld = 1024; nb = n0 - 3584; }
  int tx = threadIdx.x & 31, ty = threadIdx.x >> 5;
#pragma unroll
  for (int i = 0; i < 4; i++)
    tile[ty + i * 8][tx] = src[(size_t)(k0 + ty + i * 8) * ld + nb + tx];
  __syncthreads();
#pragma unroll
  for (int i = 0; i < 4; i++)
    Bt[(size_t)(n0 + ty + i * 8) * 1024 + k0 + tx] = f2bf(tile[tx][ty + i * 8]);
}

// ---------------- transpose+cast single square matrix (Wo): Bt[n][k] = W[k][n]
__global__ __launch_bounds__(256) void tr_one(const float* __restrict__ W,
                                              ushort* __restrict__ Bt, int N) {
  __shared__ float tile[32][33];
  int n0 = blockIdx.x * 32, k0 = blockIdx.y * 32;
  int tx = threadIdx.x & 31, ty = threadIdx.x >> 5;
#pragma unroll
  for (int i = 0; i < 4; i++)
    tile[ty + i * 8][tx] = W[(size_t)(k0 + ty + i * 8) * N + n0 + tx];
  __syncthreads();
#pragma unroll
  for (int i = 0; i < 4; i++)
    Bt[(size_t)(n0 + ty + i * 8) * 1024 + k0 + tx] = f2bf(tile[tx][ty + i * 8]);
}

// ---------------- bf16 MFMA GEMM: C[M,N](fp32, ldc) = A[M,K]bf16 @ Bt[N,K]bf16^T
// 128x128 tile, BK=32, 4 waves (2x2), each wave 64x64 via 4x4 16x16x32 MFMAs.
#define LDP 40  // padded LDS stride (ushorts): 80B -> bank stride 20 -> 2-way (free)
__global__ __launch_bounds__(256) void gemm_bf16(const ushort* __restrict__ A,
                                                 const ushort* __restrict__ Bt,
                                                 float* __restrict__ C,
                                                 int K, int ldc) {
  __shared__ __align__(16) ushort As[128][LDP];
  __shared__ __align__(16) ushort Bs[128][LDP];
  const int tid = threadIdx.x;
  const int lane = tid & 63, wave = tid >> 6;
  const int wr = wave >> 1, wc = wave & 1;
  const int row0 = blockIdx.y * 128, col0 = blockIdx.x * 128;
  const int r = tid >> 1, hf = tid & 1;

  f32x4 acc[4][4];
#pragma unroll
  for (int i = 0; i < 4; i++)
#pragma unroll
    for (int j = 0; j < 4; j++) acc[i][j] = {0.f, 0.f, 0.f, 0.f};

  const int lrow = lane & 15, lk = (lane >> 4) * 8;

  for (int k0 = 0; k0 < K; k0 += 32) {
    // stage: thread handles 32B of one row of each tile
    const float4* pa = (const float4*)(A + (size_t)(row0 + r) * K + k0 + hf * 16);
    const float4* pb = (const float4*)(Bt + (size_t)(col0 + r) * K + k0 + hf * 16);
    float4 a0 = pa[0], a1 = pa[1];
    float4 b0 = pb[0], b1 = pb[1];
    __syncthreads();  // previous compute done reading LDS
    *(float4*)&As[r][hf * 16] = a0;
    *(float4*)&As[r][hf * 16 + 8] = a1;
    *(float4*)&Bs[r][hf * 16] = b0;
    *(float4*)&Bs[r][hf * 16 + 8] = b1;
    __syncthreads();
    bfx8 af[4], bf[4];
#pragma unroll
    for (int mf = 0; mf < 4; mf++)
      af[mf] = *(const bfx8*)&As[wr * 64 + mf * 16 + lrow][lk];
#pragma unroll
    for (int nf = 0; nf < 4; nf++)
      bf[nf] = *(const bfx8*)&Bs[wc * 64 + nf * 16 + lrow][lk];
#pragma unroll
    for (int mf = 0; mf < 4; mf++)
#pragma unroll
      for (int nf = 0; nf < 4; nf++)
        acc[mf][nf] = __builtin_amdgcn_mfma_f32_16x16x32_bf16(af[mf], bf[nf], acc[mf][nf], 0, 0, 0);
  }
  // epilogue: C/D layout col=lane&15, row=(lane>>4)*4+reg  [m89/m91 verified]
  const int crow = (lane >> 4) * 4, ccol = lane & 15;
#pragma unroll
  for (int mf = 0; mf < 4; mf++)
#pragma unroll
    for (int nf = 0; nf < 4; nf++)
#pragma unroll
      for (int rr = 0; rr < 4; rr++)
        C[(size_t)(row0 + wr * 64 + mf * 16 + crow + rr) * ldc + col0 + wc * 64 + nf * 16 + ccol] =
            acc[mf][nf][rr];
}

// ---------------- beta / gamma tiny projections with fused activations
// NOTE: g buffer now stores gamma = exp(g) (scan only ever uses exp(g))
__global__ __launch_bounds__(256) void proj_bg(const float* __restrict__ hs,
                                               const float* __restrict__ Wb,
                                               const float* __restrict__ Wa,
                                               const float* __restrict__ A_log,
                                               const float* __restrict__ dt_bias,
                                               float* __restrict__ beta,
                                               float* __restrict__ g) {
  int row = blockIdx.x;
  int lane = threadIdx.x & 63;
  int wave = threadIdx.x >> 6;
  const float* x = hs + (size_t)row * HID;
  for (int out = wave; out < 12; out += 4) {
    float sum = 0.f;
    if (out < 8) {
      for (int k = lane; k < HID; k += 64) sum = fmaf(x[k], Wb[(size_t)k * 8 + out], sum);
    } else {
      int c = out - 8;
      for (int k = lane; k < HID; k += 64) sum = fmaf(x[k], Wa[(size_t)k * 4 + c], sum);
    }
    sum = wave_sum(sum);
    if (lane == 0) {
      if (out < 8) {
        beta[(size_t)row * 8 + out] = 2.f / (1.f + expf(-sum));
      } else {
        int h = out - 8;
        float xx = sum + dt_bias[h];
        float sp = (xx > 20.f) ? xx : log1pf(expf(xx));
        g[(size_t)row * 4 + h] = expf(-expf(A_log[h]) * sp);  // gamma = exp(g)
      }
    }
  }
}

// ---------------- causal depthwise conv(K=4) + SiLU (+ optional l2norm over D)
template <int D, bool NORM>
__global__ __launch_bounds__(D) void conv_silu(const float* __restrict__ x, int ldx,
                                               const float* __restrict__ w,
                                               float* __restrict__ y,
                                               int T, int C, int G, float eps) {
  int rb = blockIdx.x;
  int gi = rb % G;
  int bt = rb / G;
  int t = bt % T;
  int b = bt / T;
  int c = gi * D + threadIdx.x;
  const float* wc = w + (size_t)c * KSZ;
  float acc = 0.f;
#pragma unroll
  for (int i = 0; i < KSZ; i++) {
    int tt = t - (KSZ - 1) + i;
    if (tt >= 0) acc = fmaf(x[(size_t)(b * T + tt) * ldx + c], wc[i], acc);
  }
  float val = acc / (1.f + expf(-acc));
  if constexpr (NORM) {
    float ss = wave_sum(val * val);
    constexpr int NW = D / 64;
    __shared__ float sred[NW];
    if ((threadIdx.x & 63) == 0) sred[threadIdx.x >> 6] = ss;
    __syncthreads();
    float tot = 0.f;
#pragma unroll
    for (int i = 0; i < NW; i++) tot += sred[i];
    val *= rsqrtf(tot + eps);
  }
  y[(size_t)(b * T + t) * C + c] = val;
}

// ---------------- cross dots: d01 = k0.k1, e0 = q.k0, e1 = q.k1 per (bt,h)
__global__ __launch_bounds__(256) void cross_dots(const float* __restrict__ q,
                                                  const float* __restrict__ k,
                                                  float* __restrict__ dots) {
  int idx = blockIdx.x * 4 + (threadIdx.x >> 6);  // bt*H + h
  int lane = threadIdx.x & 63;
  int bt = idx >> 2, h = idx & 3;
  const float2* q2 = (const float2*)q;
  const float2* k2 = (const float2*)k;
  float2 qq = q2[((size_t)bt * H + h) * 64 + lane];
  float2 ka = k2[((size_t)(bt * NH + 0) * H + h) * 64 + lane];
  float2 kb = k2[((size_t)(bt * NH + 1) * H + h) * 64 + lane];
  float d01 = ka.x * kb.x + ka.y * kb.y;
  float e0 = qq.x * ka.x + qq.y * ka.y;
  float e1 = qq.x * kb.x + qq.y * kb.y;
  dpp_sum3(d01, e0, e1);
  if (lane == 0) {
    float4 o4 = {d01, e0, e1, 0.f};
    *(float4*)&dots[(size_t)idx * 4] = o4;
  }
}

// ---------------- sequential gated-delta scan, one wave per (b,h,dv-column)
// XCD-local: bh = blockIdx%8 pins each (b,h)'s 64 blocks to one XCD (L2-resident).
// All addressing wave-uniform (readfirstlane col/wave): per-lane loads are
// uniform_base[lane] (saddr+voffset), uniform values (v/beta/gamma/dots) become
// scalar loads with FIFO state in SGPRs -- kills the ~50 VALU/step of address math.
__global__ __launch_bounds__(256, 2) void scan_kernel(const float* __restrict__ q,
                                                      const float* __restrict__ k,
                                                      const float* __restrict__ v,
                                                      const float* __restrict__ beta,
                                                      const float* __restrict__ gam,
                                                      const float* __restrict__ dots,
                                                      float* __restrict__ o,
                                                      int T) {
  const int lane = threadIdx.x & 63;
  const int wave = __builtin_amdgcn_readfirstlane(threadIdx.x >> 6);
  const int bh = blockIdx.x & 7;   // -> XCD-local
  const int cb = blockIdx.x >> 3;
  const int b = bh >> 2, h = bh & 3;
  const int col = cb * 4 + wave;   // wave-uniform
  const float2* __restrict__ k2 = (const float2*)k;
  const float2* __restrict__ q2 = (const float2*)q;
  const float4* __restrict__ d4 = (const float4*)dots;
  float2 s = {0.f, 0.f};

  const int bT = b * T;
  // uniform base indices at t=0 (k2/q2 in float2 units)
  const int ik0 = bT * 512 + h * 64;           // += 512/t ; +256 for head-copy 1
  const int iq0 = bT * 256 + h * 64;           // += 256/t
  const int iv0 = bT * 2048 + h * DV + col;    // += 2048/t ; +1024 for copy 1
  const int ib0 = bT * 8 + h;                  // += 8/t ; +4
  const int ig0 = bT * 4 + h;                  // += 4/t  (same formula for d4)
  const int io0 = bT * NTOT + h * 256 + col;   // += NTOT/t

  float2 Aka, Akb, Aqq; float Ava, Avb, Abea, Abeb, Agg; float4 Add;
  float2 Bka, Bkb, Bqq; float Bva, Bvb, Bbea, Bbeb, Bgg; float4 Bdd;
  float2 Cka, Ckb, Cqq; float Cva, Cvb, Cbea, Cbeb, Cgg; float4 Cdd;
  float2 Dka, Dkb, Dqq; float Dva, Dvb, Dbea, Dbeb, Dgg; float4 Ddd;

#define LOADQ(P, tt) { \
    const float2* kp_ = k2 + ik0 + (tt) * 512; \
    const float2* qp_ = q2 + iq0 + (tt) * 256; \
    const float* vp_ = v + iv0 + (tt) * 2048; \
    const float* bp_ = beta + ib0 + (tt) * 8; \
    P##ka = kp_[lane]; \
    P##kb = kp_[256 + lane]; \
    P##qq = qp_[lane]; \
    P##va = vp_[0]; \
    P##vb = vp_[1024]; \
    P##bea = bp_[0]; \
    P##beb = bp_[4]; \
    P##gg = gam[ig0 + (tt) * 4]; \
    P##dd = d4[ig0 + (tt) * 4]; }

#define STEPQ(P, tt) { \
    float gm = P##gg; \
    float p0 = P##ka.x * s.x + P##ka.y * s.y; \
    float p1 = P##kb.x * s.x + P##kb.y * s.y; \
    float pq = P##qq.x * s.x + P##qq.y * s.y; \
    dpp_sum3(p0, p1, pq); \
    float gb0 = P##bea * gm, gb1 = P##beb * gm, bd = P##beb * P##dd.x; \
    float t0 = P##bea * P##va, t1 = P##beb * P##vb; \
    float c0 = fmaf(-gb0, p0, t0); \
    float c1 = fmaf(-bd, c0, fmaf(-gb1, p1, t1)); \
    float ov = fmaf(c1, P##dd.z, fmaf(c0, P##dd.y, gm * pq)); \
    s.x = fmaf(gm, s.x, fmaf(c0, P##ka.x, c1 * P##kb.x)); \
    s.y = fmaf(gm, s.y, fmaf(c0, P##ka.y, c1 * P##kb.y)); \
    if (lane == 0) o[io0 + (tt) * NTOT] = ov; }

  LOADQ(A, 0)
  LOADQ(B, 1)
  LOADQ(C, 2)
  LOADQ(D, 3)
  int t = 0;
  for (; t + 4 < T; t += 4) {
    STEPQ(A, t)     LOADQ(A, t + 4)
    STEPQ(B, t + 1) LOADQ(B, t + 5)
    STEPQ(C, t + 2) LOADQ(C, t + 6)
    STEPQ(D, t + 3) LOADQ(D, t + 7)
  }
  STEPQ(A, t)
  STEPQ(B, t + 1)
  STEPQ(C, t + 2)
  STEPQ(D, t + 3)
#undef LOADQ
#undef STEPQ
}

// ---------------- RMSNorm(o) * w * SiLU(gate); writes dense bf16 [M][1024]
__global__ __launch_bounds__(256) void post_norm_gate(const float* __restrict__ o,
                                                      const float* __restrict__ gate,
                                                      const float* __restrict__ w,
                                                      ushort* __restrict__ obf) {
  int rb = blockIdx.x;  // bt*H + h
  int bt = rb >> 2, h = rb & 3;
  int tid = threadIdx.x;
  size_t ob = (size_t)bt * NTOT + h * 256 + tid;
  float ov = o[ob];
  float ss = wave_sum(ov * ov);
  __shared__ float sred[4];
  if ((tid & 63) == 0) sred[tid >> 6] = ss;
  __syncthreads();
  float tot = sred[0] + sred[1] + sred[2] + sred[3];
  float rms = rsqrtf(tot * (1.f / 256.f) + 1e-5f);
  float gt = gate[(size_t)bt * NTOT + h * 256 + tid];
  float val = ov * rms * w[tid] * (gt / (1.f + expf(-gt)));
  obf[(size_t)bt * HID + h * 256 + tid] = f2bf(val);
}

extern "C" void kernel_launch(void* const* d_in, const int* in_sizes, int n_in,
                              void* d_out, int out_size, void* d_ws, size_t ws_size,
                              hipStream_t stream) {
  const float* hs      = (const float*)d_in[0];
  const float* Wq      = (const float*)d_in[1];
  const float* Wk      = (const float*)d_in[2];
  const float* Wv      = (const float*)d_in[3];
  const float* Wb      = (const float*)d_in[4];
  const float* Wa      = (const float*)d_in[5];
  const float* Wg      = (const float*)d_in[6];
  const float* Wo      = (const float*)d_in[7];
  const float* A_log   = (const float*)d_in[8];
  const float* dt_bias = (const float*)d_in[9];
  const float* wq_conv = (const float*)d_in[10];
  const float* wk_conv = (const float*)d_in[11];
  const float* wv_conv = (const float*)d_in[12];
  const float* o_w     = (const float*)d_in[13];
  float* out = (float*)d_out;

  const int B = 2, T = 1024, M = B * T;

  float* ws    = (float*)d_ws;
  float* qkvg  = ws;                          // M*4608 fp32; cols 0..1023 reused for o
  float* kbuf  = qkvg + (size_t)M * NTOT;     // M*1024 fp32
  float* vbuf  = kbuf + (size_t)M * 1024;     // M*2048 fp32
  float* betab = vbuf + (size_t)M * 2048;     // M*8
  float* gb    = betab + (size_t)M * 8;       // M*4 (gamma = exp(g))
  float* dotsb = gb + (size_t)M * 4;          // M*H*4
  float* qbuf  = out;                         // M*512 scratch in d_out; overwritten at end

  // time-disjoint bf16 aliases inside kbuf/vbuf regions:
  ushort* bqkvgT = (ushort*)kbuf;
  ushort* hsb    = (ushort*)(vbuf + (size_t)524288);  // vbuf + 2MB
  ushort* woT = (ushort*)kbuf;
  ushort* obf = (ushort*)vbuf;

  // casts
  cast_hs<<<(M * HID / 4) / 256, 256, 0, stream>>>(hs, hsb);
  tr_pack<<<dim3(NTOT / 32, HID / 32), 256, 0, stream>>>(Wq, Wk, Wv, Wg, bqkvgT);
  // fused projections (bf16 MFMA) -> packed fp32 [M,4608]
  gemm_bf16<<<dim3(NTOT / 128, M / 128), 256, 0, stream>>>(hsb, bqkvgT, qkvg, HID, NTOT);
  // beta / gamma
  proj_bg<<<M, 256, 0, stream>>>(hs, Wb, Wa, A_log, dt_bias, betab, gb);
  // conv + SiLU (+ l2norm for q,k); overwrite kbuf/vbuf (bf16 staging dead now)
  conv_silu<128, true><<<M * 4, 128, 0, stream>>>(qkvg + 0, NTOT, wq_conv, qbuf, T, 512, 4, 1e-6f);
  conv_silu<128, true><<<M * 8, 128, 0, stream>>>(qkvg + 512, NTOT, wk_conv, kbuf, T, 1024, 8, 1e-6f);
  conv_silu<256, false><<<M * 8, 256, 0, stream>>>(qkvg + 1536, NTOT, wv_conv, vbuf, T, 2048, 8, 1e-6f);
  // cross dots (on post-conv q,k)
  cross_dots<<<M * H / 4, 256, 0, stream>>>(qbuf, kbuf, dotsb);
  // scan: o written strided into qkvg cols 0..1023
  scan_kernel<<<512, 256, 0, stream>>>(qbuf, kbuf, vbuf, betab, gb, dotsb, qkvg, T);
  // epilogue norm/gate -> dense bf16 obf (vbuf region, dead after scan)
  post_norm_gate<<<M * H, 256, 0, stream>>>(qkvg, qkvg + 3584, o_w, obf);
  // output projection (bf16 MFMA): Wo^T cast into kbuf region (dead after scan)
  tr_one<<<dim3(HID / 32, HID / 32), 256, 0, stream>>>(Wo, woT, HID);
  gemm_bf16<<<dim3(HID / 128, M / 128), 256, 0, stream>>>(obf, woT, out, HID, HID);
}